// Round 4
// baseline (652.232 us; speedup 1.0000x reference)
//
#include <hip/hip_runtime.h>

// GCN 2-layer + linear head, fp32 compute, fp16 intermediate storage.
// Round-13: occupancy via *fitting* the budget, not forcing it.
//   R12 post-mortem: uncapped, the allocator balloons k_l1/k_l2 to 256 VGPR
//   -> 2 waves/SIMD, latency-bound gathers crawl (k_l2 79us, VALU 18%).
//   R11 post-mortem: capping at 84 with an 8-wide gather (live ~100) spills.
//   Fix: 4-wide gather unroll (live ~50) + pipelined index load, then
//   __launch_bounds__(256,6) -> 84-VGPR budget, 6 waves/SIMD, zero spills.
//   memset : zero per-bucket cursors
//   k_bin1 : LDS histogram over dst>>8, per-(block,digit) global reservation
//   k_bin2 : per-bucket counting sort -> sorted u16 lists, rowptr/cnt/dinv,
//            xs = fp16(x*dinv)
//   k_l1   : fused agg1+dense1 (64 nodes/block)
//   k_l2   : fused agg2+dense2+head (32 nodes/block)

typedef _Float16 half_t;
typedef _Float16 h8 __attribute__((ext_vector_type(8)));
typedef unsigned short u16;
typedef unsigned int u32;

#define BCAP1 6144   // per-bucket capacity; mean 4096, std 64 -> >30 sigma safe
#define EPB   4096   // edges per k_bin1 block -> 196 blocks at E=800k

__global__ __launch_bounds__(512) void k_bin1(const int* __restrict__ src,
                                              const int* __restrict__ dst,
                                              int* gcur, u32* __restrict__ bin1, int E) {
    __shared__ u32 hist[256], base[256];
    int tid = threadIdx.x;
    if (tid < 256) hist[tid] = 0;
    __syncthreads();
    int e0 = blockIdx.x * EPB;
#pragma unroll
    for (int j = 0; j < EPB / 512; j++) {
        int e = e0 + j * 512 + tid;
        if (e < E) atomicAdd(&hist[((u32)dst[e]) >> 8], 1u);
    }
    __syncthreads();
    if (tid < 256) {
        u32 h = hist[tid];
        base[tid] = h ? (u32)atomicAdd(&gcur[tid], (int)h) : 0u;
        hist[tid] = 0;  // reuse as local cursor
    }
    __syncthreads();
#pragma unroll
    for (int j = 0; j < EPB / 512; j++) {
        int e = e0 + j * 512 + tid;
        if (e < E) {
            u32 d = (u32)dst[e], s = (u32)src[e];
            u32 dig = d >> 8;
            u32 p = base[dig] + atomicAdd(&hist[dig], 1u);
            if (p < (u32)BCAP1) bin1[(size_t)dig * BCAP1 + p] = ((d & 255u) << 16) | s;
        }
    }
}

// One block (512 thr) per bucket: bin by dst&255, emit sorted u16 src lists
// (4-aligned starts), rowptr/cnt/dinv, and pre-scaled xs for 256 nodes.
__global__ __launch_bounds__(512) void k_bin2(const u32* __restrict__ bin1,
        const int* __restrict__ gcur, const float* __restrict__ x,
        u16* __restrict__ sorted, int* __restrict__ rowptr, int* __restrict__ cnt,
        float* __restrict__ dinv, half_t* __restrict__ xs, int n) {
    __shared__ u32 c256[256], off[256], cur[256];
    __shared__ u32 outb32[BCAP1 / 2];   // 12 KB
    __shared__ float sdiv[256];
    u16* outb = (u16*)outb32;
    int b = blockIdx.x, tid = threadIdx.x;
    int m = min(gcur[b], BCAP1);
    if (tid < 256) c256[tid] = 0;
    __syncthreads();
    const u32* in = bin1 + (size_t)b * BCAP1;
    for (int i = tid; i < m; i += 512) atomicAdd(&c256[in[i] >> 16], 1u);
    __syncthreads();
    u32 v = 0, mystart = 0;
    if (tid < 256) {
        v = (c256[tid] + 3u) & ~3u;     // 4-aligned list start (ushort4 loads)
        off[tid] = v;
    }
    __syncthreads();
    for (int o = 1; o < 256; o <<= 1) { // Hillis-Steele inclusive scan
        u32 t2 = 0;
        if (tid < 256 && tid >= o) t2 = off[tid - o];
        __syncthreads();
        if (tid < 256) off[tid] += t2;
        __syncthreads();
    }
    if (tid < 256) {
        mystart = off[tid] - v;
        cur[tid] = mystart;
    }
    __syncthreads();
    for (int i = tid; i < m; i += 512) {
        u32 w = in[i];
        u32 p = atomicAdd(&cur[w >> 16], 1u);
        if (p < (u32)BCAP1) outb[p] = (u16)(w & 0xFFFFu);
    }
    if (tid < 256) {
        int node = b * 256 + tid;
        float di = 0.f;
        if (node < n) {
            int deg = (int)c256[tid];
            di = rsqrtf((float)(deg + 1));  // +1 self loop
            cnt[node] = deg;
            rowptr[node] = b * BCAP1 + (int)mystart;
            dinv[node] = di;
        }
        sdiv[tid] = di;
    }
    u32 total = off[255];
    __syncthreads();
    u32 nw = (total < (u32)BCAP1 ? total : (u32)BCAP1) >> 1;  // u32 words
    u32* out32 = (u32*)(sorted + (size_t)b * BCAP1);
    for (u32 i = tid; i < nw; i += 512) out32[i] = outb32[i];
    // xs = fp16(x * dinv) for this block's nodes (coalesced)
    int nn = n - b * 256; if (nn > 256) nn = 256;
    for (int i = tid; i < nn * 4; i += 512) {
        int nl = i >> 2, c = i & 3;
        float d2 = sdiv[nl];
        const float4* xp = (const float4*)(x + ((size_t)(b * 256 + nl)) * 32 + c * 8);
        float4 A = xp[0], B = xp[1];
        h8 o;
        o[0] = (half_t)(A.x * d2); o[1] = (half_t)(A.y * d2);
        o[2] = (half_t)(A.z * d2); o[3] = (half_t)(A.w * d2);
        o[4] = (half_t)(B.x * d2); o[5] = (half_t)(B.y * d2);
        o[6] = (half_t)(B.z * d2); o[7] = (half_t)(B.w * d2);
        *(h8*)(xs + ((size_t)(b * 256 + nl)) * 32 + c * 8) = o;
    }
}

// Fused layer 1: gather (thread = node,q of 4) -> LDS row -> dense GEMV.
// 64 nodes per 256-thread block. 4-wide pipelined gather; dense in wc[16]
// chunks. Live set ~50 VGPR -> fits the 84-reg budget of (256,6).
__global__ __launch_bounds__(256, 6) void k_l1(
        const half_t* __restrict__ xs, const float* __restrict__ dinv,
        const int* __restrict__ rowptr, const int* __restrict__ cnt,
        const u16* __restrict__ sorted,
        const float* __restrict__ W1, const float* __restrict__ b1,
        half_t* __restrict__ h1s, int n) {
    __shared__ __attribute__((aligned(16))) float sAgg[64][32];
    __shared__ float sDi[64];
    int tid = threadIdx.x;
    int nl = tid >> 2, q = tid & 3;
    int node = blockIdx.x * 64 + nl;
    float acc[8];
#pragma unroll
    for (int k = 0; k < 8; k++) acc[k] = 0.f;
    int deg = 0;
    const u16* rb = sorted;
    float di = 0.f;
    if (node < n) {
        di = dinv[node];
        deg = cnt[node];
        rb = sorted + rowptr[node];
        h8 sv = *(const h8*)(xs + (size_t)node * 32 + q * 8);
#pragma unroll
        for (int k = 0; k < 8; k++) acc[k] = (float)sv[k];
    }
    int e = 0;
    if (deg >= 4) {
        ushort4 i4 = *(const ushort4*)(rb);
        for (; e + 8 <= deg; e += 4) {
            ushort4 nx = *(const ushort4*)(rb + e + 4);   // pipelined index load
            h8 r0 = *(const h8*)(xs + (size_t)i4.x * 32 + q * 8);
            h8 r1 = *(const h8*)(xs + (size_t)i4.y * 32 + q * 8);
            h8 r2 = *(const h8*)(xs + (size_t)i4.z * 32 + q * 8);
            h8 r3 = *(const h8*)(xs + (size_t)i4.w * 32 + q * 8);
#pragma unroll
            for (int k = 0; k < 8; k++)
                acc[k] += ((float)r0[k] + (float)r1[k]) + ((float)r2[k] + (float)r3[k]);
            i4 = nx;
        }
        {   // last full quad (i4 already holds rb[e..e+4))
            h8 r0 = *(const h8*)(xs + (size_t)i4.x * 32 + q * 8);
            h8 r1 = *(const h8*)(xs + (size_t)i4.y * 32 + q * 8);
            h8 r2 = *(const h8*)(xs + (size_t)i4.z * 32 + q * 8);
            h8 r3 = *(const h8*)(xs + (size_t)i4.w * 32 + q * 8);
#pragma unroll
            for (int k = 0; k < 8; k++)
                acc[k] += ((float)r0[k] + (float)r1[k]) + ((float)r2[k] + (float)r3[k]);
            e += 4;
        }
    }
    for (; e < deg; e++) {
        h8 r = *(const h8*)(xs + (size_t)rb[e] * 32 + q * 8);
#pragma unroll
        for (int k = 0; k < 8; k++) acc[k] += (float)r[k];
    }
    // stage di-scaled agg row into LDS
    *(float4*)&sAgg[nl][q * 8] =
        make_float4(acc[0] * di, acc[1] * di, acc[2] * di, acc[3] * di);
    *(float4*)&sAgg[nl][q * 8 + 4] =
        make_float4(acc[4] * di, acc[5] * di, acc[6] * di, acc[7] * di);
    if (q == 0) sDi[nl] = di;
    __syncthreads();
    // dense: wave w computes nodes w*16..w*16+15, lane = output feature f.
    int w = tid >> 6, f = tid & 63;
    float b1f = b1[f];
    float hacc[16];
#pragma unroll
    for (int j = 0; j < 16; j++) hacc[j] = 0.f;
#pragma unroll
    for (int kb = 0; kb < 32; kb += 16) {
        float wc[16];
#pragma unroll
        for (int k = 0; k < 16; k++) wc[k] = W1[(kb + k) * 64 + f];
#pragma unroll
        for (int j = 0; j < 16; j++) {
            int l = w * 16 + j;
#pragma unroll
            for (int k = 0; k < 16; k += 4) {
                float4 a4 = *(const float4*)&sAgg[l][kb + k];
                hacc[j] += a4.x * wc[k] + a4.y * wc[k + 1]
                         + a4.z * wc[k + 2] + a4.w * wc[k + 3];
            }
        }
    }
    int nb = blockIdx.x * 64;
#pragma unroll
    for (int j = 0; j < 16; j++) {
        int l = w * 16 + j;
        int nd = nb + l;
        if (nd < n)
            h1s[(size_t)nd * 64 + f] = (half_t)(fmaxf(hacc[j] + b1f, 0.f) * sDi[l]);
    }
}

// Fused layer 2 + head: gather (thread = node,q of 8) -> LDS row -> dense GEMV
// -> head shfl-reduce. 32 nodes per 256-thread block.
__global__ __launch_bounds__(256, 6) void k_l2(
        const half_t* __restrict__ h1s, const float* __restrict__ dinv,
        const int* __restrict__ rowptr, const int* __restrict__ cnt,
        const u16* __restrict__ sorted,
        const float* __restrict__ W2, const float* __restrict__ b2,
        const float* __restrict__ Wl, const float* __restrict__ bl,
        float* __restrict__ out, int n) {
    __shared__ __attribute__((aligned(16))) float sAgg[32][64];
    int tid = threadIdx.x;
    int nl = tid >> 3, q = tid & 7;
    int node = blockIdx.x * 32 + nl;
    float acc[8];
#pragma unroll
    for (int k = 0; k < 8; k++) acc[k] = 0.f;
    int deg = 0;
    const u16* rb = sorted;
    float di = 0.f;
    if (node < n) {
        di = dinv[node];
        deg = cnt[node];
        rb = sorted + rowptr[node];
        h8 sv = *(const h8*)(h1s + (size_t)node * 64 + q * 8);
#pragma unroll
        for (int k = 0; k < 8; k++) acc[k] = (float)sv[k];
    }
    int e = 0;
    if (deg >= 4) {
        ushort4 i4 = *(const ushort4*)(rb);
        for (; e + 8 <= deg; e += 4) {
            ushort4 nx = *(const ushort4*)(rb + e + 4);   // pipelined index load
            h8 r0 = *(const h8*)(h1s + (size_t)i4.x * 64 + q * 8);
            h8 r1 = *(const h8*)(h1s + (size_t)i4.y * 64 + q * 8);
            h8 r2 = *(const h8*)(h1s + (size_t)i4.z * 64 + q * 8);
            h8 r3 = *(const h8*)(h1s + (size_t)i4.w * 64 + q * 8);
#pragma unroll
            for (int k = 0; k < 8; k++)
                acc[k] += ((float)r0[k] + (float)r1[k]) + ((float)r2[k] + (float)r3[k]);
            i4 = nx;
        }
        {   // last full quad
            h8 r0 = *(const h8*)(h1s + (size_t)i4.x * 64 + q * 8);
            h8 r1 = *(const h8*)(h1s + (size_t)i4.y * 64 + q * 8);
            h8 r2 = *(const h8*)(h1s + (size_t)i4.z * 64 + q * 8);
            h8 r3 = *(const h8*)(h1s + (size_t)i4.w * 64 + q * 8);
#pragma unroll
            for (int k = 0; k < 8; k++)
                acc[k] += ((float)r0[k] + (float)r1[k]) + ((float)r2[k] + (float)r3[k]);
            e += 4;
        }
    }
    for (; e < deg; e++) {
        h8 r = *(const h8*)(h1s + (size_t)rb[e] * 64 + q * 8);
#pragma unroll
        for (int k = 0; k < 8; k++) acc[k] += (float)r[k];
    }
    *(float4*)&sAgg[nl][q * 8] =
        make_float4(acc[0] * di, acc[1] * di, acc[2] * di, acc[3] * di);
    *(float4*)&sAgg[nl][q * 8 + 4] =
        make_float4(acc[4] * di, acc[5] * di, acc[6] * di, acc[7] * di);
    __syncthreads();
    // dense + head: wave w computes nodes w*8..w*8+7, lane = feature f.
    int w = tid >> 6, f = tid & 63;
    float b2f = b2[f], wl0 = Wl[f * 2], wl1 = Wl[f * 2 + 1];
    float bl0 = bl[0], bl1 = bl[1];
    float hacc[8];
#pragma unroll
    for (int j = 0; j < 8; j++) hacc[j] = 0.f;
#pragma unroll
    for (int kb = 0; kb < 64; kb += 16) {
        float wc[16];
#pragma unroll
        for (int k = 0; k < 16; k++) wc[k] = W2[(kb + k) * 64 + f];
#pragma unroll
        for (int j = 0; j < 8; j++) {
            int l = w * 8 + j;
#pragma unroll
            for (int k = 0; k < 16; k += 4) {
                float4 a4 = *(const float4*)&sAgg[l][kb + k];
                hacc[j] += a4.x * wc[k] + a4.y * wc[k + 1]
                         + a4.z * wc[k + 2] + a4.w * wc[k + 3];
            }
        }
    }
    int nb = blockIdx.x * 32;
#pragma unroll
    for (int j = 0; j < 8; j++) {
        int nd = nb + w * 8 + j;
        float h2 = fmaxf(hacc[j] + b2f, 0.f);
        float q0 = h2 * wl0, q1 = h2 * wl1;
        for (int off = 32; off > 0; off >>= 1) {
            q0 += __shfl_down(q0, off);
            q1 += __shfl_down(q1, off);
        }
        if (f == 0 && nd < n)
            *(float2*)(out + (size_t)nd * 2) = make_float2(q0 + bl0, q1 + bl1);
    }
}

extern "C" void kernel_launch(void* const* d_in, const int* in_sizes, int n_in,
                              void* d_out, int out_size, void* d_ws, size_t ws_size,
                              hipStream_t stream) {
    const float* x  = (const float*)d_in[0];
    const int*   ei = (const int*)d_in[1];
    const float* W1 = (const float*)d_in[2];
    const float* b1 = (const float*)d_in[3];
    const float* W2 = (const float*)d_in[4];
    const float* b2 = (const float*)d_in[5];
    const float* Wl = (const float*)d_in[6];
    const float* bl = (const float*)d_in[7];
    float* out = (float*)d_out;

    const int n = in_sizes[0] / 32;
    const int E = in_sizes[1] / 2;
    const int* src = ei;
    const int* dst = ei + E;
    const int nbuck = (n + 255) >> 8;   // 196 for n=50000 (must be <= 256)

    size_t off = 0;
    auto alloc = [&](size_t bytes) {
        size_t o = off;
        off += (bytes + 255) & ~(size_t)255;
        return o;
    };
    char* ws = (char*)d_ws;
    int*    gcur   = (int*)(ws + alloc(256 * 4));
    u32*    bin1   = (u32*)(ws + alloc((size_t)nbuck * BCAP1 * 4));
    u16*    sorted = (u16*)(ws + alloc((size_t)nbuck * BCAP1 * 2));
    int*    rowptr = (int*)(ws + alloc((size_t)n * 4));
    int*    cnt    = (int*)(ws + alloc((size_t)n * 4));
    float*  dinv   = (float*)(ws + alloc((size_t)n * 4));
    half_t* h1s    = (half_t*)(ws + alloc((size_t)n * 64 * 2));
    half_t* xs     = (half_t*)(ws + alloc((size_t)n * 32 * 2));
    (void)ws_size;

    const int nb_b1 = (E + EPB - 1) / EPB;
    const int nb_l1 = (n + 63) / 64;
    const int nb_l2 = (n + 31) / 32;

    hipMemsetAsync(gcur, 0, 256 * 4, stream);
    k_bin1<<<nb_b1, 512, 0, stream>>>(src, dst, gcur, bin1, E);
    k_bin2<<<nbuck, 512, 0, stream>>>(bin1, gcur, x, sorted, rowptr, cnt, dinv, xs, n);
    k_l1<<<nb_l1, 256, 0, stream>>>(xs, dinv, rowptr, cnt, sorted, W1, b1, h1s, n);
    k_l2<<<nb_l2, 256, 0, stream>>>(h1s, dinv, rowptr, cnt, sorted, W2, b2, Wl, bl, out, n);
}

// Round 7
// 601.344 us; speedup vs baseline: 1.0846x; 1.0846x over previous
//
#include <hip/hip_runtime.h>

// GCN 2-layer + linear head, fp32 compute, fp16 intermediate storage.
// Round-16 (R14 hypothesis, third submission; R14/R15 were broker infra
// failures, kernel never ran). Pin the allocator at the 128-VGPR step.
//   Ledger: R10 non-chunked dense, no bounds -> 140us total (natural alloc
//           likely ~128). R12 chunked dense, no bounds -> VGPR ballooned to
//           256, 2 waves/SIMD, k_l2=79us, 216us total. R11/R13 capped 84 ->
//           array demotion to scratch, VGPR=40, 712MB writes, 376us k_l2.
//   This round: 8-wide gather (ILP~8, live ~110 regs) + chunked wc[16]
//   dense + __launch_bounds__(256,4): budget 128 fits the live set, no
//   ballooning, no demotion. Tripwire: VGPR~40 + WRITE>100MB = demoted.
//   memset : zero per-bucket cursors
//   k_bin1 : LDS histogram over dst>>8, per-(block,digit) global reservation
//   k_bin2 : per-bucket counting sort -> sorted u16 lists, rowptr/cnt/dinv,
//            xs = fp16(x*dinv)
//   k_l1   : fused agg1+dense1 (64 nodes/block)
//   k_l2   : fused agg2+dense2+head (32 nodes/block)

typedef _Float16 half_t;
typedef _Float16 h8 __attribute__((ext_vector_type(8)));
typedef unsigned short u16;
typedef unsigned int u32;

#define BCAP1 6144   // per-bucket capacity; mean 4096, std 64 -> >30 sigma safe
#define EPB   4096   // edges per k_bin1 block -> 196 blocks at E=800k

__global__ __launch_bounds__(512) void k_bin1(const int* __restrict__ src,
                                              const int* __restrict__ dst,
                                              int* gcur, u32* __restrict__ bin1, int E) {
    __shared__ u32 hist[256], base[256];
    int tid = threadIdx.x;
    if (tid < 256) hist[tid] = 0;
    __syncthreads();
    int e0 = blockIdx.x * EPB;
#pragma unroll
    for (int j = 0; j < EPB / 512; j++) {
        int e = e0 + j * 512 + tid;
        if (e < E) atomicAdd(&hist[((u32)dst[e]) >> 8], 1u);
    }
    __syncthreads();
    if (tid < 256) {
        u32 h = hist[tid];
        base[tid] = h ? (u32)atomicAdd(&gcur[tid], (int)h) : 0u;
        hist[tid] = 0;  // reuse as local cursor
    }
    __syncthreads();
#pragma unroll
    for (int j = 0; j < EPB / 512; j++) {
        int e = e0 + j * 512 + tid;
        if (e < E) {
            u32 d = (u32)dst[e], s = (u32)src[e];
            u32 dig = d >> 8;
            u32 p = base[dig] + atomicAdd(&hist[dig], 1u);
            if (p < (u32)BCAP1) bin1[(size_t)dig * BCAP1 + p] = ((d & 255u) << 16) | s;
        }
    }
}

// One block (512 thr) per bucket: bin by dst&255, emit sorted u16 src lists
// (4-aligned starts), rowptr/cnt/dinv, and pre-scaled xs for 256 nodes.
__global__ __launch_bounds__(512) void k_bin2(const u32* __restrict__ bin1,
        const int* __restrict__ gcur, const float* __restrict__ x,
        u16* __restrict__ sorted, int* __restrict__ rowptr, int* __restrict__ cnt,
        float* __restrict__ dinv, half_t* __restrict__ xs, int n) {
    __shared__ u32 c256[256], off[256], cur[256];
    __shared__ u32 outb32[BCAP1 / 2];   // 12 KB
    __shared__ float sdiv[256];
    u16* outb = (u16*)outb32;
    int b = blockIdx.x, tid = threadIdx.x;
    int m = min(gcur[b], BCAP1);
    if (tid < 256) c256[tid] = 0;
    __syncthreads();
    const u32* in = bin1 + (size_t)b * BCAP1;
    for (int i = tid; i < m; i += 512) atomicAdd(&c256[in[i] >> 16], 1u);
    __syncthreads();
    u32 v = 0, mystart = 0;
    if (tid < 256) {
        v = (c256[tid] + 3u) & ~3u;     // 4-aligned list start (ushort4 loads)
        off[tid] = v;
    }
    __syncthreads();
    for (int o = 1; o < 256; o <<= 1) { // Hillis-Steele inclusive scan
        u32 t2 = 0;
        if (tid < 256 && tid >= o) t2 = off[tid - o];
        __syncthreads();
        if (tid < 256) off[tid] += t2;
        __syncthreads();
    }
    if (tid < 256) {
        mystart = off[tid] - v;
        cur[tid] = mystart;
    }
    __syncthreads();
    for (int i = tid; i < m; i += 512) {
        u32 w = in[i];
        u32 p = atomicAdd(&cur[w >> 16], 1u);
        if (p < (u32)BCAP1) outb[p] = (u16)(w & 0xFFFFu);
    }
    if (tid < 256) {
        int node = b * 256 + tid;
        float di = 0.f;
        if (node < n) {
            int deg = (int)c256[tid];
            di = rsqrtf((float)(deg + 1));  // +1 self loop
            cnt[node] = deg;
            rowptr[node] = b * BCAP1 + (int)mystart;
            dinv[node] = di;
        }
        sdiv[tid] = di;
    }
    u32 total = off[255];
    __syncthreads();
    u32 nw = (total < (u32)BCAP1 ? total : (u32)BCAP1) >> 1;  // u32 words
    u32* out32 = (u32*)(sorted + (size_t)b * BCAP1);
    for (u32 i = tid; i < nw; i += 512) out32[i] = outb32[i];
    // xs = fp16(x * dinv) for this block's nodes (coalesced)
    int nn = n - b * 256; if (nn > 256) nn = 256;
    for (int i = tid; i < nn * 4; i += 512) {
        int nl = i >> 2, c = i & 3;
        float d2 = sdiv[nl];
        const float4* xp = (const float4*)(x + ((size_t)(b * 256 + nl)) * 32 + c * 8);
        float4 A = xp[0], B = xp[1];
        h8 o;
        o[0] = (half_t)(A.x * d2); o[1] = (half_t)(A.y * d2);
        o[2] = (half_t)(A.z * d2); o[3] = (half_t)(A.w * d2);
        o[4] = (half_t)(B.x * d2); o[5] = (half_t)(B.y * d2);
        o[6] = (half_t)(B.z * d2); o[7] = (half_t)(B.w * d2);
        *(h8*)(xs + ((size_t)(b * 256 + nl)) * 32 + c * 8) = o;
    }
}

// Fused layer 1: gather (thread = node,q of 4) -> LDS row -> dense GEMV.
// 64 nodes per 256-thread block. 8-wide gather; dense in wc[16] chunks.
// launch_bounds(256,4): 128-VGPR budget fits the ~110-reg gather live set.
__global__ __launch_bounds__(256, 4) void k_l1(
        const half_t* __restrict__ xs, const float* __restrict__ dinv,
        const int* __restrict__ rowptr, const int* __restrict__ cnt,
        const u16* __restrict__ sorted,
        const float* __restrict__ W1, const float* __restrict__ b1,
        half_t* __restrict__ h1s, int n) {
    __shared__ __attribute__((aligned(16))) float sAgg[64][32];
    __shared__ float sDi[64];
    int tid = threadIdx.x;
    int nl = tid >> 2, q = tid & 3;
    int node = blockIdx.x * 64 + nl;
    float acc[8];
#pragma unroll
    for (int k = 0; k < 8; k++) acc[k] = 0.f;
    int deg = 0;
    const u16* rb = sorted;
    float di = 0.f;
    if (node < n) {
        di = dinv[node];
        deg = cnt[node];
        rb = sorted + rowptr[node];
        h8 sv = *(const h8*)(xs + (size_t)node * 32 + q * 8);
#pragma unroll
        for (int k = 0; k < 8; k++) acc[k] = (float)sv[k];
    }
    int e = 0;
    for (; e + 8 <= deg; e += 8) {
        ushort4 i4 = *(const ushort4*)(rb + e);
        ushort4 j4 = *(const ushort4*)(rb + e + 4);
        h8 r0 = *(const h8*)(xs + (size_t)i4.x * 32 + q * 8);
        h8 r1 = *(const h8*)(xs + (size_t)i4.y * 32 + q * 8);
        h8 r2 = *(const h8*)(xs + (size_t)i4.z * 32 + q * 8);
        h8 r3 = *(const h8*)(xs + (size_t)i4.w * 32 + q * 8);
        h8 r4 = *(const h8*)(xs + (size_t)j4.x * 32 + q * 8);
        h8 r5 = *(const h8*)(xs + (size_t)j4.y * 32 + q * 8);
        h8 r6 = *(const h8*)(xs + (size_t)j4.z * 32 + q * 8);
        h8 r7 = *(const h8*)(xs + (size_t)j4.w * 32 + q * 8);
#pragma unroll
        for (int k = 0; k < 8; k++)
            acc[k] += (((float)r0[k] + (float)r1[k]) + ((float)r2[k] + (float)r3[k]))
                    + (((float)r4[k] + (float)r5[k]) + ((float)r6[k] + (float)r7[k]));
    }
    if (e + 4 <= deg) {
        ushort4 i4 = *(const ushort4*)(rb + e);
        h8 r0 = *(const h8*)(xs + (size_t)i4.x * 32 + q * 8);
        h8 r1 = *(const h8*)(xs + (size_t)i4.y * 32 + q * 8);
        h8 r2 = *(const h8*)(xs + (size_t)i4.z * 32 + q * 8);
        h8 r3 = *(const h8*)(xs + (size_t)i4.w * 32 + q * 8);
#pragma unroll
        for (int k = 0; k < 8; k++)
            acc[k] += ((float)r0[k] + (float)r1[k]) + ((float)r2[k] + (float)r3[k]);
        e += 4;
    }
    for (; e < deg; e++) {
        h8 r = *(const h8*)(xs + (size_t)rb[e] * 32 + q * 8);
#pragma unroll
        for (int k = 0; k < 8; k++) acc[k] += (float)r[k];
    }
    // stage di-scaled agg row into LDS
    *(float4*)&sAgg[nl][q * 8] =
        make_float4(acc[0] * di, acc[1] * di, acc[2] * di, acc[3] * di);
    *(float4*)&sAgg[nl][q * 8 + 4] =
        make_float4(acc[4] * di, acc[5] * di, acc[6] * di, acc[7] * di);
    if (q == 0) sDi[nl] = di;
    __syncthreads();
    // dense: wave w computes nodes w*16..w*16+15, lane = output feature f.
    int w = tid >> 6, f = tid & 63;
    float b1f = b1[f];
    float hacc[16];
#pragma unroll
    for (int j = 0; j < 16; j++) hacc[j] = 0.f;
#pragma unroll
    for (int kb = 0; kb < 32; kb += 16) {
        float wc[16];
#pragma unroll
        for (int k = 0; k < 16; k++) wc[k] = W1[(kb + k) * 64 + f];
#pragma unroll
        for (int j = 0; j < 16; j++) {
            int l = w * 16 + j;
#pragma unroll
            for (int k = 0; k < 16; k += 4) {
                float4 a4 = *(const float4*)&sAgg[l][kb + k];
                hacc[j] += a4.x * wc[k] + a4.y * wc[k + 1]
                         + a4.z * wc[k + 2] + a4.w * wc[k + 3];
            }
        }
    }
    int nb = blockIdx.x * 64;
#pragma unroll
    for (int j = 0; j < 16; j++) {
        int l = w * 16 + j;
        int nd = nb + l;
        if (nd < n)
            h1s[(size_t)nd * 64 + f] = (half_t)(fmaxf(hacc[j] + b1f, 0.f) * sDi[l]);
    }
}

// Fused layer 2 + head: gather (thread = node,q of 8) -> LDS row -> dense GEMV
// -> head shfl-reduce. 32 nodes per 256-thread block.
__global__ __launch_bounds__(256, 4) void k_l2(
        const half_t* __restrict__ h1s, const float* __restrict__ dinv,
        const int* __restrict__ rowptr, const int* __restrict__ cnt,
        const u16* __restrict__ sorted,
        const float* __restrict__ W2, const float* __restrict__ b2,
        const float* __restrict__ Wl, const float* __restrict__ bl,
        float* __restrict__ out, int n) {
    __shared__ __attribute__((aligned(16))) float sAgg[32][64];
    int tid = threadIdx.x;
    int nl = tid >> 3, q = tid & 7;
    int node = blockIdx.x * 32 + nl;
    float acc[8];
#pragma unroll
    for (int k = 0; k < 8; k++) acc[k] = 0.f;
    int deg = 0;
    const u16* rb = sorted;
    float di = 0.f;
    if (node < n) {
        di = dinv[node];
        deg = cnt[node];
        rb = sorted + rowptr[node];
        h8 sv = *(const h8*)(h1s + (size_t)node * 64 + q * 8);
#pragma unroll
        for (int k = 0; k < 8; k++) acc[k] = (float)sv[k];
    }
    int e = 0;
    for (; e + 8 <= deg; e += 8) {
        ushort4 i4 = *(const ushort4*)(rb + e);
        ushort4 j4 = *(const ushort4*)(rb + e + 4);
        h8 r0 = *(const h8*)(h1s + (size_t)i4.x * 64 + q * 8);
        h8 r1 = *(const h8*)(h1s + (size_t)i4.y * 64 + q * 8);
        h8 r2 = *(const h8*)(h1s + (size_t)i4.z * 64 + q * 8);
        h8 r3 = *(const h8*)(h1s + (size_t)i4.w * 64 + q * 8);
        h8 r4 = *(const h8*)(h1s + (size_t)j4.x * 64 + q * 8);
        h8 r5 = *(const h8*)(h1s + (size_t)j4.y * 64 + q * 8);
        h8 r6 = *(const h8*)(h1s + (size_t)j4.z * 64 + q * 8);
        h8 r7 = *(const h8*)(h1s + (size_t)j4.w * 64 + q * 8);
#pragma unroll
        for (int k = 0; k < 8; k++)
            acc[k] += (((float)r0[k] + (float)r1[k]) + ((float)r2[k] + (float)r3[k]))
                    + (((float)r4[k] + (float)r5[k]) + ((float)r6[k] + (float)r7[k]));
    }
    if (e + 4 <= deg) {
        ushort4 i4 = *(const ushort4*)(rb + e);
        h8 r0 = *(const h8*)(h1s + (size_t)i4.x * 64 + q * 8);
        h8 r1 = *(const h8*)(h1s + (size_t)i4.y * 64 + q * 8);
        h8 r2 = *(const h8*)(h1s + (size_t)i4.z * 64 + q * 8);
        h8 r3 = *(const h8*)(h1s + (size_t)i4.w * 64 + q * 8);
#pragma unroll
        for (int k = 0; k < 8; k++)
            acc[k] += ((float)r0[k] + (float)r1[k]) + ((float)r2[k] + (float)r3[k]);
        e += 4;
    }
    for (; e < deg; e++) {
        h8 r = *(const h8*)(h1s + (size_t)rb[e] * 64 + q * 8);
#pragma unroll
        for (int k = 0; k < 8; k++) acc[k] += (float)r[k];
    }
    *(float4*)&sAgg[nl][q * 8] =
        make_float4(acc[0] * di, acc[1] * di, acc[2] * di, acc[3] * di);
    *(float4*)&sAgg[nl][q * 8 + 4] =
        make_float4(acc[4] * di, acc[5] * di, acc[6] * di, acc[7] * di);
    __syncthreads();
    // dense + head: wave w computes nodes w*8..w*8+7, lane = feature f.
    int w = tid >> 6, f = tid & 63;
    float b2f = b2[f], wl0 = Wl[f * 2], wl1 = Wl[f * 2 + 1];
    float bl0 = bl[0], bl1 = bl[1];
    float hacc[8];
#pragma unroll
    for (int j = 0; j < 8; j++) hacc[j] = 0.f;
#pragma unroll
    for (int kb = 0; kb < 64; kb += 16) {
        float wc[16];
#pragma unroll
        for (int k = 0; k < 16; k++) wc[k] = W2[(kb + k) * 64 + f];
#pragma unroll
        for (int j = 0; j < 8; j++) {
            int l = w * 8 + j;
#pragma unroll
            for (int k = 0; k < 16; k += 4) {
                float4 a4 = *(const float4*)&sAgg[l][kb + k];
                hacc[j] += a4.x * wc[k] + a4.y * wc[k + 1]
                         + a4.z * wc[k + 2] + a4.w * wc[k + 3];
            }
        }
    }
    int nb = blockIdx.x * 32;
#pragma unroll
    for (int j = 0; j < 8; j++) {
        int nd = nb + w * 8 + j;
        float h2 = fmaxf(hacc[j] + b2f, 0.f);
        float q0 = h2 * wl0, q1 = h2 * wl1;
        for (int off = 32; off > 0; off >>= 1) {
            q0 += __shfl_down(q0, off);
            q1 += __shfl_down(q1, off);
        }
        if (f == 0 && nd < n)
            *(float2*)(out + (size_t)nd * 2) = make_float2(q0 + bl0, q1 + bl1);
    }
}

extern "C" void kernel_launch(void* const* d_in, const int* in_sizes, int n_in,
                              void* d_out, int out_size, void* d_ws, size_t ws_size,
                              hipStream_t stream) {
    const float* x  = (const float*)d_in[0];
    const int*   ei = (const int*)d_in[1];
    const float* W1 = (const float*)d_in[2];
    const float* b1 = (const float*)d_in[3];
    const float* W2 = (const float*)d_in[4];
    const float* b2 = (const float*)d_in[5];
    const float* Wl = (const float*)d_in[6];
    const float* bl = (const float*)d_in[7];
    float* out = (float*)d_out;

    const int n = in_sizes[0] / 32;
    const int E = in_sizes[1] / 2;
    const int* src = ei;
    const int* dst = ei + E;
    const int nbuck = (n + 255) >> 8;   // 196 for n=50000 (must be <= 256)

    size_t off = 0;
    auto alloc = [&](size_t bytes) {
        size_t o = off;
        off += (bytes + 255) & ~(size_t)255;
        return o;
    };
    char* ws = (char*)d_ws;
    int*    gcur   = (int*)(ws + alloc(256 * 4));
    u32*    bin1   = (u32*)(ws + alloc((size_t)nbuck * BCAP1 * 4));
    u16*    sorted = (u16*)(ws + alloc((size_t)nbuck * BCAP1 * 2));
    int*    rowptr = (int*)(ws + alloc((size_t)n * 4));
    int*    cnt    = (int*)(ws + alloc((size_t)n * 4));
    float*  dinv   = (float*)(ws + alloc((size_t)n * 4));
    half_t* h1s    = (half_t*)(ws + alloc((size_t)n * 64 * 2));
    half_t* xs     = (half_t*)(ws + alloc((size_t)n * 32 * 2));
    (void)ws_size;

    const int nb_b1 = (E + EPB - 1) / EPB;
    const int nb_l1 = (n + 63) / 64;
    const int nb_l2 = (n + 31) / 32;

    hipMemsetAsync(gcur, 0, 256 * 4, stream);
    k_bin1<<<nb_b1, 512, 0, stream>>>(src, dst, gcur, bin1, E);
    k_bin2<<<nbuck, 512, 0, stream>>>(bin1, gcur, x, sorted, rowptr, cnt, dinv, xs, n);
    k_l1<<<nb_l1, 256, 0, stream>>>(xs, dinv, rowptr, cnt, sorted, W1, b1, h1s, n);
    k_l2<<<nb_l2, 256, 0, stream>>>(h1s, dinv, rowptr, cnt, sorted, W2, b2, Wl, bl, out, n);
}

// Round 8
// 211.539 us; speedup vs baseline: 3.0833x; 2.8427x over previous
//
#include <hip/hip_runtime.h>

// GCN 2-layer + linear head, fp32 compute, fp16 intermediate storage.
// Round-17: gather via global_load_lds (direct-to-LDS DMA, zero data VGPRs).
//   Allocator ledger: launch_bounds 84/128 -> wholesale array demotion to
//   scratch (VGPR 40/64, 600-700MB spill writes); unbounded -> 256 VGPR,
//   2 waves/SIMD. Structural fix: move gather data out of VGPRs entirely.
//   Per batch of 8 neighbors: 8x global_load_lds(16B) -> wait vmcnt(0) ->
//   ds_read_b128 readback + accumulate. LDS gather buffer (32KB) aliases
//   the dense-phase sAgg (phase-disjoint, barrier-separated) -> 5 blocks/CU.
//   memset : zero per-bucket cursors
//   k_bin1 : LDS histogram over dst>>8, per-(block,digit) global reservation
//   k_bin2 : per-bucket counting sort -> sorted u16 lists, rowptr/cnt/dinv,
//            xs = fp16(x*dinv)
//   k_l1   : fused agg1+dense1 (64 nodes/block), LDS-DMA gather
//   k_l2   : fused agg2+dense2+head (32 nodes/block), LDS-DMA gather

typedef _Float16 half_t;
typedef _Float16 h8 __attribute__((ext_vector_type(8)));
typedef unsigned short u16;
typedef unsigned int u32;

#define BCAP1 6144   // per-bucket capacity; mean 4096, std 64 -> >30 sigma safe
#define EPB   4096   // edges per k_bin1 block -> 196 blocks at E=800k

// global -> LDS direct DMA, 16B per lane. laddr is wave-uniform base;
// HW writes lane i's data at laddr + i*16 (m104 semantics).
#define GLD16_TO_LDS(gaddr, laddr)                                             \
    __builtin_amdgcn_global_load_lds(                                          \
        (const __attribute__((address_space(1))) unsigned int*)(const void*)(gaddr), \
        (__attribute__((address_space(3))) unsigned int*)(void*)(laddr), 16, 0, 0)

__global__ __launch_bounds__(512) void k_bin1(const int* __restrict__ src,
                                              const int* __restrict__ dst,
                                              int* gcur, u32* __restrict__ bin1, int E) {
    __shared__ u32 hist[256], base[256];
    int tid = threadIdx.x;
    if (tid < 256) hist[tid] = 0;
    __syncthreads();
    int e0 = blockIdx.x * EPB;
#pragma unroll
    for (int j = 0; j < EPB / 512; j++) {
        int e = e0 + j * 512 + tid;
        if (e < E) atomicAdd(&hist[((u32)dst[e]) >> 8], 1u);
    }
    __syncthreads();
    if (tid < 256) {
        u32 h = hist[tid];
        base[tid] = h ? (u32)atomicAdd(&gcur[tid], (int)h) : 0u;
        hist[tid] = 0;  // reuse as local cursor
    }
    __syncthreads();
#pragma unroll
    for (int j = 0; j < EPB / 512; j++) {
        int e = e0 + j * 512 + tid;
        if (e < E) {
            u32 d = (u32)dst[e], s = (u32)src[e];
            u32 dig = d >> 8;
            u32 p = base[dig] + atomicAdd(&hist[dig], 1u);
            if (p < (u32)BCAP1) bin1[(size_t)dig * BCAP1 + p] = ((d & 255u) << 16) | s;
        }
    }
}

// One block (512 thr) per bucket: bin by dst&255, emit sorted u16 src lists
// (4-aligned starts), rowptr/cnt/dinv, and pre-scaled xs for 256 nodes.
__global__ __launch_bounds__(512) void k_bin2(const u32* __restrict__ bin1,
        const int* __restrict__ gcur, const float* __restrict__ x,
        u16* __restrict__ sorted, int* __restrict__ rowptr, int* __restrict__ cnt,
        float* __restrict__ dinv, half_t* __restrict__ xs, int n) {
    __shared__ u32 c256[256], off[256], cur[256];
    __shared__ u32 outb32[BCAP1 / 2];   // 12 KB
    __shared__ float sdiv[256];
    u16* outb = (u16*)outb32;
    int b = blockIdx.x, tid = threadIdx.x;
    int m = min(gcur[b], BCAP1);
    if (tid < 256) c256[tid] = 0;
    __syncthreads();
    const u32* in = bin1 + (size_t)b * BCAP1;
    for (int i = tid; i < m; i += 512) atomicAdd(&c256[in[i] >> 16], 1u);
    __syncthreads();
    u32 v = 0, mystart = 0;
    if (tid < 256) {
        v = (c256[tid] + 3u) & ~3u;     // 4-aligned list start (ushort4 loads)
        off[tid] = v;
    }
    __syncthreads();
    for (int o = 1; o < 256; o <<= 1) { // Hillis-Steele inclusive scan
        u32 t2 = 0;
        if (tid < 256 && tid >= o) t2 = off[tid - o];
        __syncthreads();
        if (tid < 256) off[tid] += t2;
        __syncthreads();
    }
    if (tid < 256) {
        mystart = off[tid] - v;
        cur[tid] = mystart;
    }
    __syncthreads();
    for (int i = tid; i < m; i += 512) {
        u32 w = in[i];
        u32 p = atomicAdd(&cur[w >> 16], 1u);
        if (p < (u32)BCAP1) outb[p] = (u16)(w & 0xFFFFu);
    }
    if (tid < 256) {
        int node = b * 256 + tid;
        float di = 0.f;
        if (node < n) {
            int deg = (int)c256[tid];
            di = rsqrtf((float)(deg + 1));  // +1 self loop
            cnt[node] = deg;
            rowptr[node] = b * BCAP1 + (int)mystart;
            dinv[node] = di;
        }
        sdiv[tid] = di;
    }
    u32 total = off[255];
    __syncthreads();
    u32 nw = (total < (u32)BCAP1 ? total : (u32)BCAP1) >> 1;  // u32 words
    u32* out32 = (u32*)(sorted + (size_t)b * BCAP1);
    for (u32 i = tid; i < nw; i += 512) out32[i] = outb32[i];
    // xs = fp16(x * dinv) for this block's nodes (coalesced)
    int nn = n - b * 256; if (nn > 256) nn = 256;
    for (int i = tid; i < nn * 4; i += 512) {
        int nl = i >> 2, c = i & 3;
        float d2 = sdiv[nl];
        const float4* xp = (const float4*)(x + ((size_t)(b * 256 + nl)) * 32 + c * 8);
        float4 A = xp[0], B = xp[1];
        h8 o;
        o[0] = (half_t)(A.x * d2); o[1] = (half_t)(A.y * d2);
        o[2] = (half_t)(A.z * d2); o[3] = (half_t)(A.w * d2);
        o[4] = (half_t)(B.x * d2); o[5] = (half_t)(B.y * d2);
        o[6] = (half_t)(B.z * d2); o[7] = (half_t)(B.w * d2);
        *(h8*)(xs + ((size_t)(b * 256 + nl)) * 32 + c * 8) = o;
    }
}

// Fused layer 1: LDS-DMA gather (thread = node, q of 4) -> sAgg -> dense GEMV.
// 64 nodes per 256-thread block. smem: gather buf (32KB) aliases sAgg+sDi.
__global__ __launch_bounds__(256) void k_l1(
        const half_t* __restrict__ xs, const float* __restrict__ dinv,
        const int* __restrict__ rowptr, const int* __restrict__ cnt,
        const u16* __restrict__ sorted,
        const float* __restrict__ W1, const float* __restrict__ b1,
        half_t* __restrict__ h1s, int n) {
    __shared__ __attribute__((aligned(16))) char smem[32768];
    float (*sAgg)[32] = (float (*)[32])smem;              // 8 KB (phase 2)
    float* sDi = (float*)(smem + 64 * 32 * 4);            // 256 B (phase 2)
    int tid = threadIdx.x;
    int nl = tid >> 2, q = tid & 3;
    int lane = tid & 63;
    int wv = __builtin_amdgcn_readfirstlane(tid >> 6);
    char* wbuf = smem + wv * 8192;                        // 8 slots x 1024 B
    int node = blockIdx.x * 64 + nl;
    float acc[8];
#pragma unroll
    for (int k = 0; k < 8; k++) acc[k] = 0.f;
    int deg = 0;
    const u16* rb = sorted;
    float di = 0.f;
    if (node < n) {
        di = dinv[node];
        deg = cnt[node];
        rb = sorted + rowptr[node];
        h8 sv = *(const h8*)(xs + (size_t)node * 32 + q * 8);
#pragma unroll
        for (int k = 0; k < 8; k++) acc[k] = (float)sv[k];
    }
    // wave-uniform batch count (16 nodes/wave: reduce over strides 4..32)
    int wm = deg;
    wm = max(wm, __shfl_xor(wm, 4));
    wm = max(wm, __shfl_xor(wm, 8));
    wm = max(wm, __shfl_xor(wm, 16));
    wm = max(wm, __shfl_xor(wm, 32));
    int nbatch = (wm + 7) >> 3;
    ushort4 ia = make_ushort4(0, 0, 0, 0), ib = make_ushort4(0, 0, 0, 0);
    if (nbatch) { ia = *(const ushort4*)(rb); ib = *(const ushort4*)(rb + 4); }
    for (int bt = 0; bt < nbatch; ++bt) {
        int base = bt * 8;
        ushort4 iaN = ia, ibN = ib;
        if (bt + 1 < nbatch) {               // wave-uniform branch
            iaN = *(const ushort4*)(rb + base + 8);
            ibN = *(const ushort4*)(rb + base + 12);
        }
        u32 id[8] = {ia.x, ia.y, ia.z, ia.w, ib.x, ib.y, ib.z, ib.w};
#pragma unroll
        for (int d = 0; d < 8; d++) {
            u32 ii = (base + d < deg) ? id[d] : 0u;
            GLD16_TO_LDS(xs + (size_t)ii * 32 + q * 8, wbuf + d * 1024);
        }
        asm volatile("s_waitcnt vmcnt(0)" ::: "memory");
        __builtin_amdgcn_sched_barrier(0);
#pragma unroll
        for (int d = 0; d < 8; d++) {
            if (base + d < deg) {
                h8 r = *(const h8*)(wbuf + d * 1024 + lane * 16);
#pragma unroll
                for (int k = 0; k < 8; k++) acc[k] += (float)r[k];
            }
        }
        ia = iaN; ib = ibN;
    }
    __syncthreads();   // all waves done with gather buffer before sAgg reuse
    *(float4*)&sAgg[nl][q * 8] =
        make_float4(acc[0] * di, acc[1] * di, acc[2] * di, acc[3] * di);
    *(float4*)&sAgg[nl][q * 8 + 4] =
        make_float4(acc[4] * di, acc[5] * di, acc[6] * di, acc[7] * di);
    if (q == 0) sDi[nl] = di;
    __syncthreads();
    // dense: wave w computes nodes w*16..w*16+15, lane = output feature f.
    int w = tid >> 6, f = tid & 63;
    float b1f = b1[f];
    float hacc[16];
#pragma unroll
    for (int j = 0; j < 16; j++) hacc[j] = 0.f;
#pragma unroll
    for (int kb = 0; kb < 32; kb += 16) {
        float wc[16];
#pragma unroll
        for (int k = 0; k < 16; k++) wc[k] = W1[(kb + k) * 64 + f];
#pragma unroll
        for (int j = 0; j < 16; j++) {
            int l = w * 16 + j;
#pragma unroll
            for (int k = 0; k < 16; k += 4) {
                float4 a4 = *(const float4*)&sAgg[l][kb + k];
                hacc[j] += a4.x * wc[k] + a4.y * wc[k + 1]
                         + a4.z * wc[k + 2] + a4.w * wc[k + 3];
            }
        }
    }
    int nb = blockIdx.x * 64;
#pragma unroll
    for (int j = 0; j < 16; j++) {
        int l = w * 16 + j;
        int nd = nb + l;
        if (nd < n)
            h1s[(size_t)nd * 64 + f] = (half_t)(fmaxf(hacc[j] + b1f, 0.f) * sDi[l]);
    }
}

// Fused layer 2 + head: LDS-DMA gather (thread = node, q of 8) -> sAgg ->
// dense GEMV -> head shfl-reduce. 32 nodes per 256-thread block.
__global__ __launch_bounds__(256) void k_l2(
        const half_t* __restrict__ h1s, const float* __restrict__ dinv,
        const int* __restrict__ rowptr, const int* __restrict__ cnt,
        const u16* __restrict__ sorted,
        const float* __restrict__ W2, const float* __restrict__ b2,
        const float* __restrict__ Wl, const float* __restrict__ bl,
        float* __restrict__ out, int n) {
    __shared__ __attribute__((aligned(16))) char smem[32768];
    float (*sAgg)[64] = (float (*)[64])smem;              // 8 KB (phase 2)
    int tid = threadIdx.x;
    int nl = tid >> 3, q = tid & 7;
    int lane = tid & 63;
    int wv = __builtin_amdgcn_readfirstlane(tid >> 6);
    char* wbuf = smem + wv * 8192;                        // 8 slots x 1024 B
    int node = blockIdx.x * 32 + nl;
    float acc[8];
#pragma unroll
    for (int k = 0; k < 8; k++) acc[k] = 0.f;
    int deg = 0;
    const u16* rb = sorted;
    float di = 0.f;
    if (node < n) {
        di = dinv[node];
        deg = cnt[node];
        rb = sorted + rowptr[node];
        h8 sv = *(const h8*)(h1s + (size_t)node * 64 + q * 8);
#pragma unroll
        for (int k = 0; k < 8; k++) acc[k] = (float)sv[k];
    }
    // wave-uniform batch count (8 nodes/wave: reduce over strides 8..32)
    int wm = deg;
    wm = max(wm, __shfl_xor(wm, 8));
    wm = max(wm, __shfl_xor(wm, 16));
    wm = max(wm, __shfl_xor(wm, 32));
    int nbatch = (wm + 7) >> 3;
    ushort4 ia = make_ushort4(0, 0, 0, 0), ib = make_ushort4(0, 0, 0, 0);
    if (nbatch) { ia = *(const ushort4*)(rb); ib = *(const ushort4*)(rb + 4); }
    for (int bt = 0; bt < nbatch; ++bt) {
        int base = bt * 8;
        ushort4 iaN = ia, ibN = ib;
        if (bt + 1 < nbatch) {               // wave-uniform branch
            iaN = *(const ushort4*)(rb + base + 8);
            ibN = *(const ushort4*)(rb + base + 12);
        }
        u32 id[8] = {ia.x, ia.y, ia.z, ia.w, ib.x, ib.y, ib.z, ib.w};
#pragma unroll
        for (int d = 0; d < 8; d++) {
            u32 ii = (base + d < deg) ? id[d] : 0u;
            GLD16_TO_LDS(h1s + (size_t)ii * 64 + q * 8, wbuf + d * 1024);
        }
        asm volatile("s_waitcnt vmcnt(0)" ::: "memory");
        __builtin_amdgcn_sched_barrier(0);
#pragma unroll
        for (int d = 0; d < 8; d++) {
            if (base + d < deg) {
                h8 r = *(const h8*)(wbuf + d * 1024 + lane * 16);
#pragma unroll
                for (int k = 0; k < 8; k++) acc[k] += (float)r[k];
            }
        }
        ia = iaN; ib = ibN;
    }
    __syncthreads();   // all waves done with gather buffer before sAgg reuse
    *(float4*)&sAgg[nl][q * 8] =
        make_float4(acc[0] * di, acc[1] * di, acc[2] * di, acc[3] * di);
    *(float4*)&sAgg[nl][q * 8 + 4] =
        make_float4(acc[4] * di, acc[5] * di, acc[6] * di, acc[7] * di);
    __syncthreads();
    // dense + head: wave w computes nodes w*8..w*8+7, lane = feature f.
    int w = tid >> 6, f = tid & 63;
    float b2f = b2[f], wl0 = Wl[f * 2], wl1 = Wl[f * 2 + 1];
    float bl0 = bl[0], bl1 = bl[1];
    float hacc[8];
#pragma unroll
    for (int j = 0; j < 8; j++) hacc[j] = 0.f;
#pragma unroll
    for (int kb = 0; kb < 64; kb += 16) {
        float wc[16];
#pragma unroll
        for (int k = 0; k < 16; k++) wc[k] = W2[(kb + k) * 64 + f];
#pragma unroll
        for (int j = 0; j < 8; j++) {
            int l = w * 8 + j;
#pragma unroll
            for (int k = 0; k < 16; k += 4) {
                float4 a4 = *(const float4*)&sAgg[l][kb + k];
                hacc[j] += a4.x * wc[k] + a4.y * wc[k + 1]
                         + a4.z * wc[k + 2] + a4.w * wc[k + 3];
            }
        }
    }
    int nb = blockIdx.x * 32;
#pragma unroll
    for (int j = 0; j < 8; j++) {
        int nd = nb + w * 8 + j;
        float h2 = fmaxf(hacc[j] + b2f, 0.f);
        float q0 = h2 * wl0, q1 = h2 * wl1;
        for (int off = 32; off > 0; off >>= 1) {
            q0 += __shfl_down(q0, off);
            q1 += __shfl_down(q1, off);
        }
        if (f == 0 && nd < n)
            *(float2*)(out + (size_t)nd * 2) = make_float2(q0 + bl0, q1 + bl1);
    }
}

extern "C" void kernel_launch(void* const* d_in, const int* in_sizes, int n_in,
                              void* d_out, int out_size, void* d_ws, size_t ws_size,
                              hipStream_t stream) {
    const float* x  = (const float*)d_in[0];
    const int*   ei = (const int*)d_in[1];
    const float* W1 = (const float*)d_in[2];
    const float* b1 = (const float*)d_in[3];
    const float* W2 = (const float*)d_in[4];
    const float* b2 = (const float*)d_in[5];
    const float* Wl = (const float*)d_in[6];
    const float* bl = (const float*)d_in[7];
    float* out = (float*)d_out;

    const int n = in_sizes[0] / 32;
    const int E = in_sizes[1] / 2;
    const int* src = ei;
    const int* dst = ei + E;
    const int nbuck = (n + 255) >> 8;   // 196 for n=50000 (must be <= 256)

    size_t off = 0;
    auto alloc = [&](size_t bytes) {
        size_t o = off;
        off += (bytes + 255) & ~(size_t)255;
        return o;
    };
    char* ws = (char*)d_ws;
    int*    gcur   = (int*)(ws + alloc(256 * 4));
    u32*    bin1   = (u32*)(ws + alloc((size_t)nbuck * BCAP1 * 4));
    u16*    sorted = (u16*)(ws + alloc((size_t)nbuck * BCAP1 * 2));
    int*    rowptr = (int*)(ws + alloc((size_t)n * 4));
    int*    cnt    = (int*)(ws + alloc((size_t)n * 4));
    float*  dinv   = (float*)(ws + alloc((size_t)n * 4));
    half_t* h1s    = (half_t*)(ws + alloc((size_t)n * 64 * 2));
    half_t* xs     = (half_t*)(ws + alloc((size_t)n * 32 * 2));
    (void)ws_size;

    const int nb_b1 = (E + EPB - 1) / EPB;
    const int nb_l1 = (n + 63) / 64;
    const int nb_l2 = (n + 31) / 32;

    hipMemsetAsync(gcur, 0, 256 * 4, stream);
    k_bin1<<<nb_b1, 512, 0, stream>>>(src, dst, gcur, bin1, E);
    k_bin2<<<nbuck, 512, 0, stream>>>(bin1, gcur, x, sorted, rowptr, cnt, dinv, xs, n);
    k_l1<<<nb_l1, 256, 0, stream>>>(xs, dinv, rowptr, cnt, sorted, W1, b1, h1s, n);
    k_l2<<<nb_l2, 256, 0, stream>>>(h1s, dinv, rowptr, cnt, sorted, W2, b2, Wl, bl, out, n);
}

// Round 9
// 142.021 us; speedup vs baseline: 4.5925x; 1.4895x over previous
//
#include <hip/hip_runtime.h>

// GCN 2-layer + linear head, fp32 compute, fp16 intermediate storage.
// Round-18: restore the measured champion (R10 = 140.4us) exactly.
//   Post-mortem ledger: R10's profile shows k_l1/k_l2 each < 44us (all top-5
//   dispatches were 44us harness fills). The wc[16]-chunked dense phase
//   introduced in R11 ballooned the allocator to 256 VGPR (2 waves/SIMD,
//   k_l2=79us) and every later variant inherited that. launch_bounds caps
//   (84/128) both triggered wholesale array demotion (600+MB scratch).
//   DMA-gather (R17) removed data VGPRs but still ballooned to 256 and the
//   per-batch vmcnt(0) drain matched reg-gather perf (76us).
//   This round: exact R10 source to reclaim 140us AND capture the champion's
//   per-kernel counters (never measured) to guide the next step.
//   memset : zero per-bucket cursors
//   k_bin1 : LDS histogram over dst>>8, per-(block,digit) global reservation
//   k_bin2 : per-bucket counting sort -> sorted u16 lists, rowptr/cnt/dinv,
//            xs = fp16(x*dinv)
//   k_l1   : fused agg1+dense1 (64 nodes/block), non-chunked wc[32] dense
//   k_l2   : fused agg2+dense2+head (32 nodes/block), non-chunked wc[64] dense

typedef _Float16 half_t;
typedef _Float16 h8 __attribute__((ext_vector_type(8)));
typedef unsigned short u16;
typedef unsigned int u32;

#define BCAP1 6144   // per-bucket capacity; mean 4096, std 64 -> >30 sigma safe
#define EPB   4096   // edges per k_bin1 block -> 196 blocks at E=800k

__global__ __launch_bounds__(512) void k_bin1(const int* __restrict__ src,
                                              const int* __restrict__ dst,
                                              int* gcur, u32* __restrict__ bin1, int E) {
    __shared__ u32 hist[256], base[256];
    int tid = threadIdx.x;
    if (tid < 256) hist[tid] = 0;
    __syncthreads();
    int e0 = blockIdx.x * EPB;
#pragma unroll
    for (int j = 0; j < EPB / 512; j++) {
        int e = e0 + j * 512 + tid;
        if (e < E) atomicAdd(&hist[((u32)dst[e]) >> 8], 1u);
    }
    __syncthreads();
    if (tid < 256) {
        u32 h = hist[tid];
        base[tid] = h ? (u32)atomicAdd(&gcur[tid], (int)h) : 0u;
        hist[tid] = 0;  // reuse as local cursor
    }
    __syncthreads();
#pragma unroll
    for (int j = 0; j < EPB / 512; j++) {
        int e = e0 + j * 512 + tid;
        if (e < E) {
            u32 d = (u32)dst[e], s = (u32)src[e];
            u32 dig = d >> 8;
            u32 p = base[dig] + atomicAdd(&hist[dig], 1u);
            if (p < (u32)BCAP1) bin1[(size_t)dig * BCAP1 + p] = ((d & 255u) << 16) | s;
        }
    }
}

// One block (512 thr) per bucket: bin by dst&255, emit sorted u16 src lists
// (4-aligned starts), rowptr/cnt/dinv, and pre-scaled xs for 256 nodes.
__global__ __launch_bounds__(512) void k_bin2(const u32* __restrict__ bin1,
        const int* __restrict__ gcur, const float* __restrict__ x,
        u16* __restrict__ sorted, int* __restrict__ rowptr, int* __restrict__ cnt,
        float* __restrict__ dinv, half_t* __restrict__ xs, int n) {
    __shared__ u32 c256[256], off[256], cur[256];
    __shared__ u32 outb32[BCAP1 / 2];   // 12 KB
    __shared__ float sdiv[256];
    u16* outb = (u16*)outb32;
    int b = blockIdx.x, tid = threadIdx.x;
    int m = min(gcur[b], BCAP1);
    if (tid < 256) c256[tid] = 0;
    __syncthreads();
    const u32* in = bin1 + (size_t)b * BCAP1;
    for (int i = tid; i < m; i += 512) atomicAdd(&c256[in[i] >> 16], 1u);
    __syncthreads();
    u32 v = 0, mystart = 0;
    if (tid < 256) {
        v = (c256[tid] + 3u) & ~3u;     // 4-aligned list start (ushort4 loads)
        off[tid] = v;
    }
    __syncthreads();
    for (int o = 1; o < 256; o <<= 1) { // Hillis-Steele inclusive scan
        u32 t2 = 0;
        if (tid < 256 && tid >= o) t2 = off[tid - o];
        __syncthreads();
        if (tid < 256) off[tid] += t2;
        __syncthreads();
    }
    if (tid < 256) {
        mystart = off[tid] - v;
        cur[tid] = mystart;
    }
    __syncthreads();
    for (int i = tid; i < m; i += 512) {
        u32 w = in[i];
        u32 p = atomicAdd(&cur[w >> 16], 1u);
        if (p < (u32)BCAP1) outb[p] = (u16)(w & 0xFFFFu);
    }
    if (tid < 256) {
        int node = b * 256 + tid;
        float di = 0.f;
        if (node < n) {
            int deg = (int)c256[tid];
            di = rsqrtf((float)(deg + 1));  // +1 self loop
            cnt[node] = deg;
            rowptr[node] = b * BCAP1 + (int)mystart;
            dinv[node] = di;
        }
        sdiv[tid] = di;
    }
    u32 total = off[255];
    __syncthreads();
    u32 nw = (total < (u32)BCAP1 ? total : (u32)BCAP1) >> 1;  // u32 words
    u32* out32 = (u32*)(sorted + (size_t)b * BCAP1);
    for (u32 i = tid; i < nw; i += 512) out32[i] = outb32[i];
    // xs = fp16(x * dinv) for this block's nodes (coalesced)
    int nn = n - b * 256; if (nn > 256) nn = 256;
    for (int i = tid; i < nn * 4; i += 512) {
        int nl = i >> 2, c = i & 3;
        float d2 = sdiv[nl];
        const float4* xp = (const float4*)(x + ((size_t)(b * 256 + nl)) * 32 + c * 8);
        float4 A = xp[0], B = xp[1];
        h8 o;
        o[0] = (half_t)(A.x * d2); o[1] = (half_t)(A.y * d2);
        o[2] = (half_t)(A.z * d2); o[3] = (half_t)(A.w * d2);
        o[4] = (half_t)(B.x * d2); o[5] = (half_t)(B.y * d2);
        o[6] = (half_t)(B.z * d2); o[7] = (half_t)(B.w * d2);
        *(h8*)(xs + ((size_t)(b * 256 + nl)) * 32 + c * 8) = o;
    }
}

// Fused layer 1: gather (thread = node,q of 4) -> LDS row -> dense GEMV.
// 64 nodes per 256-thread block.
__global__ __launch_bounds__(256) void k_l1(
        const half_t* __restrict__ xs, const float* __restrict__ dinv,
        const int* __restrict__ rowptr, const int* __restrict__ cnt,
        const u16* __restrict__ sorted,
        const float* __restrict__ W1, const float* __restrict__ b1,
        half_t* __restrict__ h1s, int n) {
    __shared__ __attribute__((aligned(16))) float sAgg[64][32];
    __shared__ float sDi[64];
    int tid = threadIdx.x;
    int nl = tid >> 2, q = tid & 3;
    int node = blockIdx.x * 64 + nl;
    float acc[8];
#pragma unroll
    for (int k = 0; k < 8; k++) acc[k] = 0.f;
    int deg = 0;
    const u16* rb = sorted;
    if (node < n) {
        float di = dinv[node];
        deg = cnt[node];
        rb = sorted + rowptr[node];
        h8 sv = *(const h8*)(xs + (size_t)node * 32 + q * 8);
#pragma unroll
        for (int k = 0; k < 8; k++) acc[k] = (float)sv[k];
        if (q == 0) sDi[nl] = di;
    } else if (q == 0) {
        sDi[nl] = 0.f;
    }
    int e = 0;
    for (; e + 8 <= deg; e += 8) {
        ushort4 i4 = *(const ushort4*)(rb + e);
        ushort4 j4 = *(const ushort4*)(rb + e + 4);
        h8 r0 = *(const h8*)(xs + (size_t)i4.x * 32 + q * 8);
        h8 r1 = *(const h8*)(xs + (size_t)i4.y * 32 + q * 8);
        h8 r2 = *(const h8*)(xs + (size_t)i4.z * 32 + q * 8);
        h8 r3 = *(const h8*)(xs + (size_t)i4.w * 32 + q * 8);
        h8 r4 = *(const h8*)(xs + (size_t)j4.x * 32 + q * 8);
        h8 r5 = *(const h8*)(xs + (size_t)j4.y * 32 + q * 8);
        h8 r6 = *(const h8*)(xs + (size_t)j4.z * 32 + q * 8);
        h8 r7 = *(const h8*)(xs + (size_t)j4.w * 32 + q * 8);
#pragma unroll
        for (int k = 0; k < 8; k++)
            acc[k] += (((float)r0[k] + (float)r1[k]) + ((float)r2[k] + (float)r3[k]))
                    + (((float)r4[k] + (float)r5[k]) + ((float)r6[k] + (float)r7[k]));
    }
    if (e + 4 <= deg) {
        ushort4 i4 = *(const ushort4*)(rb + e);
        h8 r0 = *(const h8*)(xs + (size_t)i4.x * 32 + q * 8);
        h8 r1 = *(const h8*)(xs + (size_t)i4.y * 32 + q * 8);
        h8 r2 = *(const h8*)(xs + (size_t)i4.z * 32 + q * 8);
        h8 r3 = *(const h8*)(xs + (size_t)i4.w * 32 + q * 8);
#pragma unroll
        for (int k = 0; k < 8; k++)
            acc[k] += ((float)r0[k] + (float)r1[k]) + ((float)r2[k] + (float)r3[k]);
        e += 4;
    }
    for (; e < deg; e++) {
        h8 r = *(const h8*)(xs + (size_t)rb[e] * 32 + q * 8);
#pragma unroll
        for (int k = 0; k < 8; k++) acc[k] += (float)r[k];
    }
    // stage di-scaled agg row into LDS (write = di * acc)
    {
        float di = (node < n) ? dinv[node] : 0.f;
        *(float4*)&sAgg[nl][q * 8] =
            make_float4(acc[0] * di, acc[1] * di, acc[2] * di, acc[3] * di);
        *(float4*)&sAgg[nl][q * 8 + 4] =
            make_float4(acc[4] * di, acc[5] * di, acc[6] * di, acc[7] * di);
    }
    __syncthreads();
    // dense: wave w computes nodes w*16..w*16+15, lane = output feature f
    int w = tid >> 6, f = tid & 63;
    float wc[32];
#pragma unroll
    for (int k = 0; k < 32; k++) wc[k] = W1[k * 64 + f];
    float b1f = b1[f];
    int nb = blockIdx.x * 64;
#pragma unroll
    for (int j = 0; j < 16; j++) {
        int l = w * 16 + j;
        int nd = nb + l;
        float h = b1f;
#pragma unroll
        for (int k = 0; k < 32; k += 4) {
            float4 a4 = *(const float4*)&sAgg[l][k];
            h += a4.x * wc[k] + a4.y * wc[k + 1] + a4.z * wc[k + 2] + a4.w * wc[k + 3];
        }
        if (nd < n)
            h1s[(size_t)nd * 64 + f] = (half_t)(fmaxf(h, 0.f) * sDi[l]);
    }
}

// Fused layer 2 + head: gather (thread = node,q of 8) -> LDS row -> dense GEMV
// -> head shfl-reduce. 32 nodes per 256-thread block.
__global__ __launch_bounds__(256) void k_l2(
        const half_t* __restrict__ h1s, const float* __restrict__ dinv,
        const int* __restrict__ rowptr, const int* __restrict__ cnt,
        const u16* __restrict__ sorted,
        const float* __restrict__ W2, const float* __restrict__ b2,
        const float* __restrict__ Wl, const float* __restrict__ bl,
        float* __restrict__ out, int n) {
    __shared__ __attribute__((aligned(16))) float sAgg[32][64];
    int tid = threadIdx.x;
    int nl = tid >> 3, q = tid & 7;
    int node = blockIdx.x * 32 + nl;
    float acc[8];
#pragma unroll
    for (int k = 0; k < 8; k++) acc[k] = 0.f;
    int deg = 0;
    const u16* rb = sorted;
    float di = 0.f;
    if (node < n) {
        di = dinv[node];
        deg = cnt[node];
        rb = sorted + rowptr[node];
        h8 sv = *(const h8*)(h1s + (size_t)node * 64 + q * 8);
#pragma unroll
        for (int k = 0; k < 8; k++) acc[k] = (float)sv[k];
    }
    int e = 0;
    for (; e + 8 <= deg; e += 8) {
        ushort4 i4 = *(const ushort4*)(rb + e);
        ushort4 j4 = *(const ushort4*)(rb + e + 4);
        h8 r0 = *(const h8*)(h1s + (size_t)i4.x * 64 + q * 8);
        h8 r1 = *(const h8*)(h1s + (size_t)i4.y * 64 + q * 8);
        h8 r2 = *(const h8*)(h1s + (size_t)i4.z * 64 + q * 8);
        h8 r3 = *(const h8*)(h1s + (size_t)i4.w * 64 + q * 8);
        h8 r4 = *(const h8*)(h1s + (size_t)j4.x * 64 + q * 8);
        h8 r5 = *(const h8*)(h1s + (size_t)j4.y * 64 + q * 8);
        h8 r6 = *(const h8*)(h1s + (size_t)j4.z * 64 + q * 8);
        h8 r7 = *(const h8*)(h1s + (size_t)j4.w * 64 + q * 8);
#pragma unroll
        for (int k = 0; k < 8; k++)
            acc[k] += (((float)r0[k] + (float)r1[k]) + ((float)r2[k] + (float)r3[k]))
                    + (((float)r4[k] + (float)r5[k]) + ((float)r6[k] + (float)r7[k]));
    }
    if (e + 4 <= deg) {
        ushort4 i4 = *(const ushort4*)(rb + e);
        h8 r0 = *(const h8*)(h1s + (size_t)i4.x * 64 + q * 8);
        h8 r1 = *(const h8*)(h1s + (size_t)i4.y * 64 + q * 8);
        h8 r2 = *(const h8*)(h1s + (size_t)i4.z * 64 + q * 8);
        h8 r3 = *(const h8*)(h1s + (size_t)i4.w * 64 + q * 8);
#pragma unroll
        for (int k = 0; k < 8; k++)
            acc[k] += ((float)r0[k] + (float)r1[k]) + ((float)r2[k] + (float)r3[k]);
        e += 4;
    }
    for (; e < deg; e++) {
        h8 r = *(const h8*)(h1s + (size_t)rb[e] * 64 + q * 8);
#pragma unroll
        for (int k = 0; k < 8; k++) acc[k] += (float)r[k];
    }
    *(float4*)&sAgg[nl][q * 8] =
        make_float4(acc[0] * di, acc[1] * di, acc[2] * di, acc[3] * di);
    *(float4*)&sAgg[nl][q * 8 + 4] =
        make_float4(acc[4] * di, acc[5] * di, acc[6] * di, acc[7] * di);
    __syncthreads();
    // dense + head: wave w computes nodes w*8..w*8+7, lane = feature f
    int w = tid >> 6, f = tid & 63;
    float wc[64];
#pragma unroll
    for (int k = 0; k < 64; k++) wc[k] = W2[k * 64 + f];
    float b2f = b2[f], wl0 = Wl[f * 2], wl1 = Wl[f * 2 + 1];
    float bl0 = bl[0], bl1 = bl[1];
    int nb = blockIdx.x * 32;
#pragma unroll
    for (int j = 0; j < 8; j++) {
        int l = w * 8 + j;
        int nd = nb + l;
        float h2 = b2f;
#pragma unroll
        for (int k = 0; k < 64; k += 4) {
            float4 a4 = *(const float4*)&sAgg[l][k];
            h2 += a4.x * wc[k] + a4.y * wc[k + 1] + a4.z * wc[k + 2] + a4.w * wc[k + 3];
        }
        h2 = fmaxf(h2, 0.f);
        float q0 = h2 * wl0, q1 = h2 * wl1;
        for (int off = 32; off > 0; off >>= 1) {
            q0 += __shfl_down(q0, off);
            q1 += __shfl_down(q1, off);
        }
        if (f == 0 && nd < n)
            *(float2*)(out + (size_t)nd * 2) = make_float2(q0 + bl0, q1 + bl1);
    }
}

extern "C" void kernel_launch(void* const* d_in, const int* in_sizes, int n_in,
                              void* d_out, int out_size, void* d_ws, size_t ws_size,
                              hipStream_t stream) {
    const float* x  = (const float*)d_in[0];
    const int*   ei = (const int*)d_in[1];
    const float* W1 = (const float*)d_in[2];
    const float* b1 = (const float*)d_in[3];
    const float* W2 = (const float*)d_in[4];
    const float* b2 = (const float*)d_in[5];
    const float* Wl = (const float*)d_in[6];
    const float* bl = (const float*)d_in[7];
    float* out = (float*)d_out;

    const int n = in_sizes[0] / 32;
    const int E = in_sizes[1] / 2;
    const int* src = ei;
    const int* dst = ei + E;
    const int nbuck = (n + 255) >> 8;   // 196 for n=50000 (must be <= 256)

    size_t off = 0;
    auto alloc = [&](size_t bytes) {
        size_t o = off;
        off += (bytes + 255) & ~(size_t)255;
        return o;
    };
    char* ws = (char*)d_ws;
    int*    gcur   = (int*)(ws + alloc(256 * 4));
    u32*    bin1   = (u32*)(ws + alloc((size_t)nbuck * BCAP1 * 4));
    u16*    sorted = (u16*)(ws + alloc((size_t)nbuck * BCAP1 * 2));
    int*    rowptr = (int*)(ws + alloc((size_t)n * 4));
    int*    cnt    = (int*)(ws + alloc((size_t)n * 4));
    float*  dinv   = (float*)(ws + alloc((size_t)n * 4));
    half_t* h1s    = (half_t*)(ws + alloc((size_t)n * 64 * 2));
    half_t* xs     = (half_t*)(ws + alloc((size_t)n * 32 * 2));
    (void)ws_size;

    const int nb_b1 = (E + EPB - 1) / EPB;
    const int nb_l1 = (n + 63) / 64;
    const int nb_l2 = (n + 31) / 32;

    hipMemsetAsync(gcur, 0, 256 * 4, stream);
    k_bin1<<<nb_b1, 512, 0, stream>>>(src, dst, gcur, bin1, E);
    k_bin2<<<nbuck, 512, 0, stream>>>(bin1, gcur, x, sorted, rowptr, cnt, dinv, xs, n);
    k_l1<<<nb_l1, 256, 0, stream>>>(xs, dinv, rowptr, cnt, sorted, W1, b1, h1s, n);
    k_l2<<<nb_l2, 256, 0, stream>>>(h1s, dinv, rowptr, cnt, sorted, W2, b2, Wl, bl, out, n);
}

// Round 10
// 141.754 us; speedup vs baseline: 4.6012x; 1.0019x over previous
//
#include <hip/hip_runtime.h>

// GCN 2-layer + linear head, fp32 compute, fp16 intermediate storage.
// Round-19: champion (R18 = 142us) + __launch_bounds__(256,3) on k_l1/k_l2.
//   Occupancy-axis ledger: budget 84 -> demote (VGPR 40, 712MB scratch);
//   budget 128 -> demote (VGPR 64, 634MB); unbounded+chunked -> balloon to
//   256 VGPR (2 waves/SIMD). Budget 170 ((256,3)) is the untested point:
//   gather live ~110, dense live ~90 (disjoint phases) -> both fit with
//   slack for the pipeliner. If champion was at 256, this is 2->3 waves/SIMD
//   in the latency-bound gather. Single-attribute A/B vs R18.
//   Tripwire: VGPR<=64 + WRITE>100MB = demoted -> revert axis permanently.
//   memset : zero per-bucket cursors
//   k_bin1 : LDS histogram over dst>>8, per-(block,digit) global reservation
//   k_bin2 : per-bucket counting sort -> sorted u16 lists, rowptr/cnt/dinv,
//            xs = fp16(x*dinv)
//   k_l1   : fused agg1+dense1 (64 nodes/block), non-chunked wc[32] dense
//   k_l2   : fused agg2+dense2+head (32 nodes/block), non-chunked wc[64] dense

typedef _Float16 half_t;
typedef _Float16 h8 __attribute__((ext_vector_type(8)));
typedef unsigned short u16;
typedef unsigned int u32;

#define BCAP1 6144   // per-bucket capacity; mean 4096, std 64 -> >30 sigma safe
#define EPB   4096   // edges per k_bin1 block -> 196 blocks at E=800k

__global__ __launch_bounds__(512) void k_bin1(const int* __restrict__ src,
                                              const int* __restrict__ dst,
                                              int* gcur, u32* __restrict__ bin1, int E) {
    __shared__ u32 hist[256], base[256];
    int tid = threadIdx.x;
    if (tid < 256) hist[tid] = 0;
    __syncthreads();
    int e0 = blockIdx.x * EPB;
#pragma unroll
    for (int j = 0; j < EPB / 512; j++) {
        int e = e0 + j * 512 + tid;
        if (e < E) atomicAdd(&hist[((u32)dst[e]) >> 8], 1u);
    }
    __syncthreads();
    if (tid < 256) {
        u32 h = hist[tid];
        base[tid] = h ? (u32)atomicAdd(&gcur[tid], (int)h) : 0u;
        hist[tid] = 0;  // reuse as local cursor
    }
    __syncthreads();
#pragma unroll
    for (int j = 0; j < EPB / 512; j++) {
        int e = e0 + j * 512 + tid;
        if (e < E) {
            u32 d = (u32)dst[e], s = (u32)src[e];
            u32 dig = d >> 8;
            u32 p = base[dig] + atomicAdd(&hist[dig], 1u);
            if (p < (u32)BCAP1) bin1[(size_t)dig * BCAP1 + p] = ((d & 255u) << 16) | s;
        }
    }
}

// One block (512 thr) per bucket: bin by dst&255, emit sorted u16 src lists
// (4-aligned starts), rowptr/cnt/dinv, and pre-scaled xs for 256 nodes.
__global__ __launch_bounds__(512) void k_bin2(const u32* __restrict__ bin1,
        const int* __restrict__ gcur, const float* __restrict__ x,
        u16* __restrict__ sorted, int* __restrict__ rowptr, int* __restrict__ cnt,
        float* __restrict__ dinv, half_t* __restrict__ xs, int n) {
    __shared__ u32 c256[256], off[256], cur[256];
    __shared__ u32 outb32[BCAP1 / 2];   // 12 KB
    __shared__ float sdiv[256];
    u16* outb = (u16*)outb32;
    int b = blockIdx.x, tid = threadIdx.x;
    int m = min(gcur[b], BCAP1);
    if (tid < 256) c256[tid] = 0;
    __syncthreads();
    const u32* in = bin1 + (size_t)b * BCAP1;
    for (int i = tid; i < m; i += 512) atomicAdd(&c256[in[i] >> 16], 1u);
    __syncthreads();
    u32 v = 0, mystart = 0;
    if (tid < 256) {
        v = (c256[tid] + 3u) & ~3u;     // 4-aligned list start (ushort4 loads)
        off[tid] = v;
    }
    __syncthreads();
    for (int o = 1; o < 256; o <<= 1) { // Hillis-Steele inclusive scan
        u32 t2 = 0;
        if (tid < 256 && tid >= o) t2 = off[tid - o];
        __syncthreads();
        if (tid < 256) off[tid] += t2;
        __syncthreads();
    }
    if (tid < 256) {
        mystart = off[tid] - v;
        cur[tid] = mystart;
    }
    __syncthreads();
    for (int i = tid; i < m; i += 512) {
        u32 w = in[i];
        u32 p = atomicAdd(&cur[w >> 16], 1u);
        if (p < (u32)BCAP1) outb[p] = (u16)(w & 0xFFFFu);
    }
    if (tid < 256) {
        int node = b * 256 + tid;
        float di = 0.f;
        if (node < n) {
            int deg = (int)c256[tid];
            di = rsqrtf((float)(deg + 1));  // +1 self loop
            cnt[node] = deg;
            rowptr[node] = b * BCAP1 + (int)mystart;
            dinv[node] = di;
        }
        sdiv[tid] = di;
    }
    u32 total = off[255];
    __syncthreads();
    u32 nw = (total < (u32)BCAP1 ? total : (u32)BCAP1) >> 1;  // u32 words
    u32* out32 = (u32*)(sorted + (size_t)b * BCAP1);
    for (u32 i = tid; i < nw; i += 512) out32[i] = outb32[i];
    // xs = fp16(x * dinv) for this block's nodes (coalesced)
    int nn = n - b * 256; if (nn > 256) nn = 256;
    for (int i = tid; i < nn * 4; i += 512) {
        int nl = i >> 2, c = i & 3;
        float d2 = sdiv[nl];
        const float4* xp = (const float4*)(x + ((size_t)(b * 256 + nl)) * 32 + c * 8);
        float4 A = xp[0], B = xp[1];
        h8 o;
        o[0] = (half_t)(A.x * d2); o[1] = (half_t)(A.y * d2);
        o[2] = (half_t)(A.z * d2); o[3] = (half_t)(A.w * d2);
        o[4] = (half_t)(B.x * d2); o[5] = (half_t)(B.y * d2);
        o[6] = (half_t)(B.z * d2); o[7] = (half_t)(B.w * d2);
        *(h8*)(xs + ((size_t)(b * 256 + nl)) * 32 + c * 8) = o;
    }
}

// Fused layer 1: gather (thread = node,q of 4) -> LDS row -> dense GEMV.
// 64 nodes per 256-thread block. launch_bounds(256,3): 170-VGPR budget.
__global__ __launch_bounds__(256, 3) void k_l1(
        const half_t* __restrict__ xs, const float* __restrict__ dinv,
        const int* __restrict__ rowptr, const int* __restrict__ cnt,
        const u16* __restrict__ sorted,
        const float* __restrict__ W1, const float* __restrict__ b1,
        half_t* __restrict__ h1s, int n) {
    __shared__ __attribute__((aligned(16))) float sAgg[64][32];
    __shared__ float sDi[64];
    int tid = threadIdx.x;
    int nl = tid >> 2, q = tid & 3;
    int node = blockIdx.x * 64 + nl;
    float acc[8];
#pragma unroll
    for (int k = 0; k < 8; k++) acc[k] = 0.f;
    int deg = 0;
    const u16* rb = sorted;
    if (node < n) {
        float di = dinv[node];
        deg = cnt[node];
        rb = sorted + rowptr[node];
        h8 sv = *(const h8*)(xs + (size_t)node * 32 + q * 8);
#pragma unroll
        for (int k = 0; k < 8; k++) acc[k] = (float)sv[k];
        if (q == 0) sDi[nl] = di;
    } else if (q == 0) {
        sDi[nl] = 0.f;
    }
    int e = 0;
    for (; e + 8 <= deg; e += 8) {
        ushort4 i4 = *(const ushort4*)(rb + e);
        ushort4 j4 = *(const ushort4*)(rb + e + 4);
        h8 r0 = *(const h8*)(xs + (size_t)i4.x * 32 + q * 8);
        h8 r1 = *(const h8*)(xs + (size_t)i4.y * 32 + q * 8);
        h8 r2 = *(const h8*)(xs + (size_t)i4.z * 32 + q * 8);
        h8 r3 = *(const h8*)(xs + (size_t)i4.w * 32 + q * 8);
        h8 r4 = *(const h8*)(xs + (size_t)j4.x * 32 + q * 8);
        h8 r5 = *(const h8*)(xs + (size_t)j4.y * 32 + q * 8);
        h8 r6 = *(const h8*)(xs + (size_t)j4.z * 32 + q * 8);
        h8 r7 = *(const h8*)(xs + (size_t)j4.w * 32 + q * 8);
#pragma unroll
        for (int k = 0; k < 8; k++)
            acc[k] += (((float)r0[k] + (float)r1[k]) + ((float)r2[k] + (float)r3[k]))
                    + (((float)r4[k] + (float)r5[k]) + ((float)r6[k] + (float)r7[k]));
    }
    if (e + 4 <= deg) {
        ushort4 i4 = *(const ushort4*)(rb + e);
        h8 r0 = *(const h8*)(xs + (size_t)i4.x * 32 + q * 8);
        h8 r1 = *(const h8*)(xs + (size_t)i4.y * 32 + q * 8);
        h8 r2 = *(const h8*)(xs + (size_t)i4.z * 32 + q * 8);
        h8 r3 = *(const h8*)(xs + (size_t)i4.w * 32 + q * 8);
#pragma unroll
        for (int k = 0; k < 8; k++)
            acc[k] += ((float)r0[k] + (float)r1[k]) + ((float)r2[k] + (float)r3[k]);
        e += 4;
    }
    for (; e < deg; e++) {
        h8 r = *(const h8*)(xs + (size_t)rb[e] * 32 + q * 8);
#pragma unroll
        for (int k = 0; k < 8; k++) acc[k] += (float)r[k];
    }
    // stage di-scaled agg row into LDS (write = di * acc)
    {
        float di = (node < n) ? dinv[node] : 0.f;
        *(float4*)&sAgg[nl][q * 8] =
            make_float4(acc[0] * di, acc[1] * di, acc[2] * di, acc[3] * di);
        *(float4*)&sAgg[nl][q * 8 + 4] =
            make_float4(acc[4] * di, acc[5] * di, acc[6] * di, acc[7] * di);
    }
    __syncthreads();
    // dense: wave w computes nodes w*16..w*16+15, lane = output feature f
    int w = tid >> 6, f = tid & 63;
    float wc[32];
#pragma unroll
    for (int k = 0; k < 32; k++) wc[k] = W1[k * 64 + f];
    float b1f = b1[f];
    int nb = blockIdx.x * 64;
#pragma unroll
    for (int j = 0; j < 16; j++) {
        int l = w * 16 + j;
        int nd = nb + l;
        float h = b1f;
#pragma unroll
        for (int k = 0; k < 32; k += 4) {
            float4 a4 = *(const float4*)&sAgg[l][k];
            h += a4.x * wc[k] + a4.y * wc[k + 1] + a4.z * wc[k + 2] + a4.w * wc[k + 3];
        }
        if (nd < n)
            h1s[(size_t)nd * 64 + f] = (half_t)(fmaxf(h, 0.f) * sDi[l]);
    }
}

// Fused layer 2 + head: gather (thread = node,q of 8) -> LDS row -> dense GEMV
// -> head shfl-reduce. 32 nodes per 256-thread block. launch_bounds(256,3).
__global__ __launch_bounds__(256, 3) void k_l2(
        const half_t* __restrict__ h1s, const float* __restrict__ dinv,
        const int* __restrict__ rowptr, const int* __restrict__ cnt,
        const u16* __restrict__ sorted,
        const float* __restrict__ W2, const float* __restrict__ b2,
        const float* __restrict__ Wl, const float* __restrict__ bl,
        float* __restrict__ out, int n) {
    __shared__ __attribute__((aligned(16))) float sAgg[32][64];
    int tid = threadIdx.x;
    int nl = tid >> 3, q = tid & 7;
    int node = blockIdx.x * 32 + nl;
    float acc[8];
#pragma unroll
    for (int k = 0; k < 8; k++) acc[k] = 0.f;
    int deg = 0;
    const u16* rb = sorted;
    float di = 0.f;
    if (node < n) {
        di = dinv[node];
        deg = cnt[node];
        rb = sorted + rowptr[node];
        h8 sv = *(const h8*)(h1s + (size_t)node * 64 + q * 8);
#pragma unroll
        for (int k = 0; k < 8; k++) acc[k] = (float)sv[k];
    }
    int e = 0;
    for (; e + 8 <= deg; e += 8) {
        ushort4 i4 = *(const ushort4*)(rb + e);
        ushort4 j4 = *(const ushort4*)(rb + e + 4);
        h8 r0 = *(const h8*)(h1s + (size_t)i4.x * 64 + q * 8);
        h8 r1 = *(const h8*)(h1s + (size_t)i4.y * 64 + q * 8);
        h8 r2 = *(const h8*)(h1s + (size_t)i4.z * 64 + q * 8);
        h8 r3 = *(const h8*)(h1s + (size_t)i4.w * 64 + q * 8);
        h8 r4 = *(const h8*)(h1s + (size_t)j4.x * 64 + q * 8);
        h8 r5 = *(const h8*)(h1s + (size_t)j4.y * 64 + q * 8);
        h8 r6 = *(const h8*)(h1s + (size_t)j4.z * 64 + q * 8);
        h8 r7 = *(const h8*)(h1s + (size_t)j4.w * 64 + q * 8);
#pragma unroll
        for (int k = 0; k < 8; k++)
            acc[k] += (((float)r0[k] + (float)r1[k]) + ((float)r2[k] + (float)r3[k]))
                    + (((float)r4[k] + (float)r5[k]) + ((float)r6[k] + (float)r7[k]));
    }
    if (e + 4 <= deg) {
        ushort4 i4 = *(const ushort4*)(rb + e);
        h8 r0 = *(const h8*)(h1s + (size_t)i4.x * 64 + q * 8);
        h8 r1 = *(const h8*)(h1s + (size_t)i4.y * 64 + q * 8);
        h8 r2 = *(const h8*)(h1s + (size_t)i4.z * 64 + q * 8);
        h8 r3 = *(const h8*)(h1s + (size_t)i4.w * 64 + q * 8);
#pragma unroll
        for (int k = 0; k < 8; k++)
            acc[k] += ((float)r0[k] + (float)r1[k]) + ((float)r2[k] + (float)r3[k]);
        e += 4;
    }
    for (; e < deg; e++) {
        h8 r = *(const h8*)(h1s + (size_t)rb[e] * 64 + q * 8);
#pragma unroll
        for (int k = 0; k < 8; k++) acc[k] += (float)r[k];
    }
    *(float4*)&sAgg[nl][q * 8] =
        make_float4(acc[0] * di, acc[1] * di, acc[2] * di, acc[3] * di);
    *(float4*)&sAgg[nl][q * 8 + 4] =
        make_float4(acc[4] * di, acc[5] * di, acc[6] * di, acc[7] * di);
    __syncthreads();
    // dense + head: wave w computes nodes w*8..w*8+7, lane = feature f
    int w = tid >> 6, f = tid & 63;
    float wc[64];
#pragma unroll
    for (int k = 0; k < 64; k++) wc[k] = W2[k * 64 + f];
    float b2f = b2[f], wl0 = Wl[f * 2], wl1 = Wl[f * 2 + 1];
    float bl0 = bl[0], bl1 = bl[1];
    int nb = blockIdx.x * 32;
#pragma unroll
    for (int j = 0; j < 8; j++) {
        int l = w * 8 + j;
        int nd = nb + l;
        float h2 = b2f;
#pragma unroll
        for (int k = 0; k < 64; k += 4) {
            float4 a4 = *(const float4*)&sAgg[l][k];
            h2 += a4.x * wc[k] + a4.y * wc[k + 1] + a4.z * wc[k + 2] + a4.w * wc[k + 3];
        }
        h2 = fmaxf(h2, 0.f);
        float q0 = h2 * wl0, q1 = h2 * wl1;
        for (int off = 32; off > 0; off >>= 1) {
            q0 += __shfl_down(q0, off);
            q1 += __shfl_down(q1, off);
        }
        if (f == 0 && nd < n)
            *(float2*)(out + (size_t)nd * 2) = make_float2(q0 + bl0, q1 + bl1);
    }
}

extern "C" void kernel_launch(void* const* d_in, const int* in_sizes, int n_in,
                              void* d_out, int out_size, void* d_ws, size_t ws_size,
                              hipStream_t stream) {
    const float* x  = (const float*)d_in[0];
    const int*   ei = (const int*)d_in[1];
    const float* W1 = (const float*)d_in[2];
    const float* b1 = (const float*)d_in[3];
    const float* W2 = (const float*)d_in[4];
    const float* b2 = (const float*)d_in[5];
    const float* Wl = (const float*)d_in[6];
    const float* bl = (const float*)d_in[7];
    float* out = (float*)d_out;

    const int n = in_sizes[0] / 32;
    const int E = in_sizes[1] / 2;
    const int* src = ei;
    const int* dst = ei + E;
    const int nbuck = (n + 255) >> 8;   // 196 for n=50000 (must be <= 256)

    size_t off = 0;
    auto alloc = [&](size_t bytes) {
        size_t o = off;
        off += (bytes + 255) & ~(size_t)255;
        return o;
    };
    char* ws = (char*)d_ws;
    int*    gcur   = (int*)(ws + alloc(256 * 4));
    u32*    bin1   = (u32*)(ws + alloc((size_t)nbuck * BCAP1 * 4));
    u16*    sorted = (u16*)(ws + alloc((size_t)nbuck * BCAP1 * 2));
    int*    rowptr = (int*)(ws + alloc((size_t)n * 4));
    int*    cnt    = (int*)(ws + alloc((size_t)n * 4));
    float*  dinv   = (float*)(ws + alloc((size_t)n * 4));
    half_t* h1s    = (half_t*)(ws + alloc((size_t)n * 64 * 2));
    half_t* xs     = (half_t*)(ws + alloc((size_t)n * 32 * 2));
    (void)ws_size;

    const int nb_b1 = (E + EPB - 1) / EPB;
    const int nb_l1 = (n + 63) / 64;
    const int nb_l2 = (n + 31) / 32;

    hipMemsetAsync(gcur, 0, 256 * 4, stream);
    k_bin1<<<nb_b1, 512, 0, stream>>>(src, dst, gcur, bin1, E);
    k_bin2<<<nbuck, 512, 0, stream>>>(bin1, gcur, x, sorted, rowptr, cnt, dinv, xs, n);
    k_l1<<<nb_l1, 256, 0, stream>>>(xs, dinv, rowptr, cnt, sorted, W1, b1, h1s, n);
    k_l2<<<nb_l2, 256, 0, stream>>>(h1s, dinv, rowptr, cnt, sorted, W2, b2, Wl, bl, out, n);
}